// Round 4
// baseline (3611.288 us; speedup 1.0000x reference)
//
// Resubmit of Round-2 kernel — previous bench failed with an infra error
// ("MI355X container failed twice"), no kernel-level signal.
#include <hip/hip_runtime.h>
#include <hip/hip_bf16.h>

#define B_    128
#define P_    196
#define ENC_  2048
#define A_    512
#define E_    512
#define H_    512
#define V_    20000
#define TMAX_ 20

// ---- d_out layout (floats) ----
#define CAPLEN_OFF 51200000L
#define ALPHA_OFF  51200128L

typedef __attribute__((ext_vector_type(4))) float f32x4;
typedef __attribute__((ext_vector_type(8))) short bf16x8;

#define GLL16(gsrc, ldst) \
  __builtin_amdgcn_global_load_lds((__attribute__((address_space(1))) const void*)(gsrc), \
                                   (__attribute__((address_space(3))) void*)(ldst), 16, 0, 0)

__device__ __forceinline__ unsigned short f2b(float x) {
  union { float f; unsigned u; } v; v.f = x;
  unsigned r = v.u + 0x7FFF + ((v.u >> 16) & 1);
  return (unsigned short)(r >> 16);
}
__device__ __forceinline__ float b2f(unsigned short u) {
  union { unsigned u; float f; } v; v.u = ((unsigned)u) << 16; return v.f;
}

// ---------------------------------------------------------------------------
// Setup: predictions[:,0,:] one-hot, alphas[:,0,:]=0, caplen as float, h=0.
__global__ __launch_bounds__(256) void k_setup(const int* __restrict__ caplen,
                                               float* __restrict__ out,
                                               float* __restrict__ h,
                                               unsigned short* __restrict__ h_bf) {
  long idx = (long)blockIdx.x * 256 + threadIdx.x;
  if (idx < (long)B_ * V_) {
    long b = idx / V_, v = idx % V_;
    out[b * (long)TMAX_ * V_ + v] = (v == 1) ? 1.0f : 0.0f;
  }
  if (idx < B_) out[CAPLEN_OFF + idx] = (float)caplen[idx];
  if (idx < (long)B_ * P_) {
    long b = idx / P_, p = idx % P_;
    out[ALPHA_OFF + b * (long)(TMAX_ * P_) + p] = 0.0f;
  }
  if (idx < B_ * H_) { h[idx] = 0.0f; h_bf[idx] = 0; }
}

// ---------------------------------------------------------------------------
// Transpose + convert: src [R,C] f32 -> dst [C,R] bf16.  grid (R/32, C/32).
__global__ __launch_bounds__(256) void k_cvt_t(const float* __restrict__ src,
                                               unsigned short* __restrict__ dst,
                                               int R, int C) {
  __shared__ float tile[32][33];
  int lx = threadIdx.x & 31, ly = threadIdx.x >> 5;
  int r0 = blockIdx.x * 32, c0 = blockIdx.y * 32;
#pragma unroll
  for (int j = 0; j < 32; j += 8)
    tile[ly + j][lx] = src[(long)(r0 + ly + j) * C + c0 + lx];
  __syncthreads();
#pragma unroll
  for (int j = 0; j < 32; j += 8)
    dst[(long)(c0 + ly + j) * R + r0 + lx] = f2b(tile[lx][ly + j]);
}

// Wo [20000,512] f32 -> Wo_bf [20096,512] bf16 (pad rows zero). grid 5024.
__global__ __launch_bounds__(256) void k_cvt_wo(const float* __restrict__ Wo,
                                                unsigned short* __restrict__ Wo_bf) {
  long gid = (long)blockIdx.x * 256 + threadIdx.x;
  long base = gid * 8;
  if (base >= (long)20096 * 512) return;
  long row = base >> 9;
  bf16x8 u;
  if (row < V_) {
    float4 f0 = *(const float4*)(Wo + base);
    float4 f1 = *(const float4*)(Wo + base + 4);
    u[0] = (short)f2b(f0.x); u[1] = (short)f2b(f0.y);
    u[2] = (short)f2b(f0.z); u[3] = (short)f2b(f0.w);
    u[4] = (short)f2b(f1.x); u[5] = (short)f2b(f1.y);
    u[6] = (short)f2b(f1.z); u[7] = (short)f2b(f1.w);
  } else {
    for (int j = 0; j < 8; ++j) u[j] = 0;
  }
  *(bf16x8*)(Wo_bf + base) = u;
}

// img f32 -> img_bf bf16, 8 elems/thread.  grid 25088.
__global__ __launch_bounds__(256) void k_cvt_img(const float* __restrict__ img,
                                                 unsigned short* __restrict__ img_bf) {
  long base = ((long)blockIdx.x * 256 + threadIdx.x) * 8;
  float4 f0 = *(const float4*)(img + base);
  float4 f1 = *(const float4*)(img + base + 4);
  bf16x8 u;
  u[0] = (short)f2b(f0.x); u[1] = (short)f2b(f0.y);
  u[2] = (short)f2b(f0.z); u[3] = (short)f2b(f0.w);
  u[4] = (short)f2b(f1.x); u[5] = (short)f2b(f1.y);
  u[6] = (short)f2b(f1.z); u[7] = (short)f2b(f1.w);
  *(bf16x8*)(img_bf + base) = u;
}

// ---------------------------------------------------------------------------
// MFMA NT GEMM: C[M,N] = A_bf[M,K] @ B_bf[N,K]^T + bias.
// Tile 128x128, BK=32, 4 waves (2x2 of 64x64), 16x16x32 bf16 MFMA.
// OBF=1 -> bf16 output, OBF=0 -> f32 output.  bias may be null.
template <int OBF>
__global__ __launch_bounds__(256) void k_gemm_nt(const unsigned short* __restrict__ Abf,
                                                 const unsigned short* __restrict__ Bbf,
                                                 const float* __restrict__ bias,
                                                 void* __restrict__ Cv, long ldc,
                                                 int N, int K) {
  __shared__ unsigned short As[4096];
  __shared__ unsigned short Bs[4096];
  int tid = threadIdx.x, wave = tid >> 6, lane = tid & 63;
  int m0 = blockIdx.x * 128, n0 = blockIdx.y * 128;
  int wm = (wave & 1) * 64, wn = (wave >> 1) * 64;
  int rowL = tid >> 2, chkL = (tid & 3) * 8;
  const unsigned short* gA0 = Abf + (long)(m0 + rowL) * K + chkL;
  const unsigned short* gA1 = gA0 + (long)64 * K;
  const unsigned short* gB0 = Bbf + (long)(n0 + rowL) * K + chkL;
  const unsigned short* gB1 = gB0 + (long)64 * K;
  unsigned short* ldsA = As + wave * 512;
  unsigned short* ldsB = Bs + wave * 512;

  f32x4 acc[4][4];
#pragma unroll
  for (int i = 0; i < 4; ++i)
#pragma unroll
    for (int j = 0; j < 4; ++j) acc[i][j] = (f32x4){0.f, 0.f, 0.f, 0.f};

  int fm = lane & 15, q8 = (lane >> 4) * 8;
  for (int kc = 0; kc < K; kc += 32) {
    GLL16(gA0 + kc, ldsA);
    GLL16(gA1 + kc, ldsA + 2048);
    GLL16(gB0 + kc, ldsB);
    GLL16(gB1 + kc, ldsB + 2048);
    __syncthreads();
    bf16x8 af[4], bfr[4];
#pragma unroll
    for (int i = 0; i < 4; ++i)
      af[i] = *(const bf16x8*)&As[(wm + i * 16 + fm) * 32 + q8];
#pragma unroll
    for (int j = 0; j < 4; ++j)
      bfr[j] = *(const bf16x8*)&Bs[(wn + j * 16 + fm) * 32 + q8];
#pragma unroll
    for (int i = 0; i < 4; ++i)
#pragma unroll
      for (int j = 0; j < 4; ++j)
        acc[i][j] = __builtin_amdgcn_mfma_f32_16x16x32_bf16(af[i], bfr[j], acc[i][j], 0, 0, 0);
    __syncthreads();
  }
  int q4 = (lane >> 4) * 4;
#pragma unroll
  for (int i = 0; i < 4; ++i)
#pragma unroll
    for (int j = 0; j < 4; ++j) {
      int n = n0 + wn + j * 16 + fm;
      if (n < N) {
        float bv = bias ? bias[n] : 0.f;
#pragma unroll
        for (int r = 0; r < 4; ++r) {
          long m = m0 + wm + i * 16 + q4 + r;
          if (OBF) ((unsigned short*)Cv)[m * ldc + n] = f2b(acc[i][j][r] + bv);
          else     ((float*)Cv)[m * ldc + n] = acc[i][j][r] + bv;
        }
      }
    }
}

// ---------------------------------------------------------------------------
// Fallback att1 MFMA (f32 A with fused convert) — only used if img_bf absent.
__global__ __launch_bounds__(256) void k_mfma_att1(const float* __restrict__ Aimg,
                                                   const unsigned short* __restrict__ Bbf,
                                                   const float* __restrict__ bias,
                                                   unsigned short* __restrict__ C) {
  __shared__ unsigned short As[4096];
  __shared__ unsigned short Bs[4096];
  int tid = threadIdx.x, wave = tid >> 6, lane = tid & 63;
  int m0 = blockIdx.x * 128, n0 = blockIdx.y * 128;
  int wm = (wave & 1) * 64, wn = (wave >> 1) * 64;
  int rowA = tid >> 1, segA = (tid & 1) * 16;
  const float* gA = Aimg + (long)(m0 + rowA) * ENC_ + segA;
  int rowL = tid >> 2, chkL = (tid & 3) * 8;
  const unsigned short* gB0 = Bbf + (long)(n0 + rowL) * ENC_ + chkL;
  const unsigned short* gB1 = gB0 + (long)64 * ENC_;
  unsigned short* ldsB = Bs + wave * 512;

  f32x4 acc[4][4];
#pragma unroll
  for (int i = 0; i < 4; ++i)
#pragma unroll
    for (int j = 0; j < 4; ++j) acc[i][j] = (f32x4){0.f, 0.f, 0.f, 0.f};

  int fm = lane & 15, q8 = (lane >> 4) * 8;
  for (int kc = 0; kc < ENC_; kc += 32) {
    GLL16(gB0 + kc, ldsB);
    GLL16(gB1 + kc, ldsB + 2048);
    float4 f0 = *(const float4*)(gA + kc);
    float4 f1 = *(const float4*)(gA + kc + 4);
    float4 f2 = *(const float4*)(gA + kc + 8);
    float4 f3 = *(const float4*)(gA + kc + 12);
    bf16x8 u0, u1;
    u0[0] = (short)f2b(f0.x); u0[1] = (short)f2b(f0.y);
    u0[2] = (short)f2b(f0.z); u0[3] = (short)f2b(f0.w);
    u0[4] = (short)f2b(f1.x); u0[5] = (short)f2b(f1.y);
    u0[6] = (short)f2b(f1.z); u0[7] = (short)f2b(f1.w);
    u1[0] = (short)f2b(f2.x); u1[1] = (short)f2b(f2.y);
    u1[2] = (short)f2b(f2.z); u1[3] = (short)f2b(f2.w);
    u1[4] = (short)f2b(f3.x); u1[5] = (short)f2b(f3.y);
    u1[6] = (short)f2b(f3.z); u1[7] = (short)f2b(f3.w);
    *(bf16x8*)&As[rowA * 32 + segA] = u0;
    *(bf16x8*)&As[rowA * 32 + segA + 8] = u1;
    __syncthreads();
    bf16x8 af[4], bfr[4];
#pragma unroll
    for (int i = 0; i < 4; ++i)
      af[i] = *(const bf16x8*)&As[(wm + i * 16 + fm) * 32 + q8];
#pragma unroll
    for (int j = 0; j < 4; ++j)
      bfr[j] = *(const bf16x8*)&Bs[(wn + j * 16 + fm) * 32 + q8];
#pragma unroll
    for (int i = 0; i < 4; ++i)
#pragma unroll
      for (int j = 0; j < 4; ++j)
        acc[i][j] = __builtin_amdgcn_mfma_f32_16x16x32_bf16(af[i], bfr[j], acc[i][j], 0, 0, 0);
    __syncthreads();
  }
  int q4 = (lane >> 4) * 4;
#pragma unroll
  for (int i = 0; i < 4; ++i)
#pragma unroll
    for (int j = 0; j < 4; ++j) {
      int n = n0 + wn + j * 16 + fm;
      float bv = bias[n];
#pragma unroll
      for (int r = 0; r < 4; ++r) {
        long m = m0 + wm + i * 16 + q4 + r;
        C[m * 512 + n] = f2b(acc[i][j][r] + bv);
      }
    }
}

// ---------------------------------------------------------------------------
// scores + softmax + alpha.  One block per b.  Also zeroes ctx[b,:] for the
// atomic-accumulate ctx kernel that follows (stream-ordered).
__global__ __launch_bounds__(256) void k_attn_score(const unsigned short* __restrict__ att1_bf,
                                                    const float* __restrict__ att2,
                                                    const float* __restrict__ Wf,
                                                    const float* __restrict__ bfp,
                                                    float* __restrict__ alpha_ws,
                                                    float* __restrict__ out_alpha,
                                                    float* __restrict__ ctx,
                                                    int t) {
  int b = blockIdx.x, tid = threadIdx.x;
  int wave = tid >> 6, lane = tid & 63;
  __shared__ float sc[P_ + 4];
  __shared__ float red[8];

  // zero ctx row for this b (consumed by k_attn_ctx2's atomics)
  {
    float4 z4 = {0.f, 0.f, 0.f, 0.f};
    float* c = ctx + (long)b * ENC_ + tid * 8;
    *(float4*)c = z4;
    *(float4*)(c + 4) = z4;
  }

  float a2[8], w8[8];
  {
    const float* ap = att2 + (long)b * 512 + lane * 8;
    float4 x0 = *(const float4*)ap, x1 = *(const float4*)(ap + 4);
    a2[0] = x0.x; a2[1] = x0.y; a2[2] = x0.z; a2[3] = x0.w;
    a2[4] = x1.x; a2[5] = x1.y; a2[6] = x1.z; a2[7] = x1.w;
    const float* wp = Wf + lane * 8;
    float4 y0 = *(const float4*)wp, y1 = *(const float4*)(wp + 4);
    w8[0] = y0.x; w8[1] = y0.y; w8[2] = y0.z; w8[3] = y0.w;
    w8[4] = y1.x; w8[5] = y1.y; w8[6] = y1.z; w8[7] = y1.w;
  }
  float bias0 = bfp[0];

  for (int p = wave; p < P_; p += 4) {
    bf16x8 v = *(const bf16x8*)(att1_bf + ((long)(b * P_ + p)) * 512 + lane * 8);
    float part = 0.f;
#pragma unroll
    for (int j = 0; j < 8; ++j) {
      float x = b2f((unsigned short)v[j]) + a2[j];
      part = fmaf(fmaxf(x, 0.f), w8[j], part);
    }
#pragma unroll
    for (int off = 32; off > 0; off >>= 1) part += __shfl_down(part, off);
    if (lane == 0) sc[p] = part + bias0;
  }
  __syncthreads();

  float mv = (tid < P_) ? sc[tid] : -1e30f;
#pragma unroll
  for (int off = 32; off > 0; off >>= 1) mv = fmaxf(mv, __shfl_down(mv, off));
  if (lane == 0) red[wave] = mv;
  __syncthreads();
  if (tid == 0) red[4] = fmaxf(fmaxf(red[0], red[1]), fmaxf(red[2], red[3]));
  __syncthreads();
  float mx = red[4];
  float e = (tid < P_) ? __expf(sc[tid] - mx) : 0.f;
  float sm = e;
#pragma unroll
  for (int off = 32; off > 0; off >>= 1) sm += __shfl_down(sm, off);
  if (lane == 0) red[wave] = sm;
  __syncthreads();
  if (tid == 0) red[5] = red[0] + red[1] + red[2] + red[3];
  __syncthreads();
  float inv = 1.f / red[5];
  if (tid < P_) {
    float al = e * inv;
    alpha_ws[b * P_ + tid] = al;
    out_alpha[((long)b * TMAX_ + t) * P_ + tid] = al;
  }
}

// ---------------------------------------------------------------------------
// ctx accumulate, p-split: grid (128, 7).  Each block: 28 full-ENC rows,
// perfectly coalesced 4KB row loads, atomicAdd partial into ctx (pre-zeroed).
__global__ __launch_bounds__(256) void k_attn_ctx2(const unsigned short* __restrict__ img_bf,
                                                   const float* __restrict__ alpha_ws,
                                                   float* __restrict__ ctx) {
  int b = blockIdx.x, pc = blockIdx.y;
  int tid = threadIdx.x;
  __shared__ float als[28];
  if (tid < 28) als[tid] = alpha_ws[b * P_ + pc * 28 + tid];
  __syncthreads();
  float acc[8];
#pragma unroll
  for (int j = 0; j < 8; ++j) acc[j] = 0.f;
  const unsigned short* base = img_bf + ((long)b * P_ + pc * 28) * ENC_ + tid * 8;
#pragma unroll 4
  for (int p = 0; p < 28; ++p) {
    bf16x8 v = *(const bf16x8*)(base + (long)p * ENC_);
    float al = als[p];
#pragma unroll
    for (int j = 0; j < 8; ++j) acc[j] = fmaf(al, b2f((unsigned short)v[j]), acc[j]);
  }
  float* c = ctx + (long)b * ENC_ + tid * 8;
#pragma unroll
  for (int j = 0; j < 8; ++j) atomicAdd(c + j, acc[j]);
}

// Fallback ctx (f32 img, no img_bf).  grid (128, 4).
__global__ __launch_bounds__(256) void k_attn_ctx(const float* __restrict__ img,
                                                  const float* __restrict__ alpha_ws,
                                                  float* __restrict__ ctx) {
  int b = blockIdx.x, ec = blockIdx.y;
  int tid = threadIdx.x, wave = tid >> 6, lane = tid & 63;
  __shared__ float als[P_];
  __shared__ float part[4][512];
  if (tid < P_) als[tid] = alpha_ws[b * P_ + tid];
  __syncthreads();
  float acc[8];
#pragma unroll
  for (int j = 0; j < 8; ++j) acc[j] = 0.f;
  long base = (long)b * P_ * ENC_ + ec * 512 + lane * 8;
  for (int p = wave; p < P_; p += 4) {
    float al = als[p];
    const float* r = img + base + (long)p * ENC_;
    float4 v0 = *(const float4*)r, v1 = *(const float4*)(r + 4);
    acc[0] = fmaf(al, v0.x, acc[0]); acc[1] = fmaf(al, v0.y, acc[1]);
    acc[2] = fmaf(al, v0.z, acc[2]); acc[3] = fmaf(al, v0.w, acc[3]);
    acc[4] = fmaf(al, v1.x, acc[4]); acc[5] = fmaf(al, v1.y, acc[5]);
    acc[6] = fmaf(al, v1.z, acc[6]); acc[7] = fmaf(al, v1.w, acc[7]);
  }
#pragma unroll
  for (int j = 0; j < 8; ++j) part[wave][lane * 8 + j] = acc[j];
  __syncthreads();
  for (int e = tid; e < 512; e += 256) {
    float s = part[0][e] + part[1][e] + part[2][e] + part[3][e];
    ctx[(long)b * ENC_ + ec * 512 + e] = s;
  }
}

// ---------------------------------------------------------------------------
// split-K GRU gate GEMM partials, f32.  grid (48, 12).
__global__ __launch_bounds__(256) void k_gru_part(const float* __restrict__ emb,
                                                  const int* __restrict__ cap,
                                                  const float* __restrict__ ctx,
                                                  const float* __restrict__ h,
                                                  const float* __restrict__ W_ih,
                                                  const float* __restrict__ W_hh,
                                                  float* __restrict__ part,
                                                  int step) {
  __shared__ float As[128][68];
  __shared__ float Ws[32][68];
  int n0 = blockIdx.x * 32;
  int c  = blockIdx.y;
  int tid = threadIdx.x;
  int ng = tid & 7, mg = tid >> 3;

  float acc[4][4];
#pragma unroll
  for (int i = 0; i < 4; ++i)
#pragma unroll
    for (int j = 0; j < 4; ++j) acc[i][j] = 0.f;

  const float* Wbase;
  long wstride;
  if (c < 10) { Wbase = W_ih + (long)n0 * 2560 + c * 256;        wstride = 2560; }
  else        { Wbase = W_hh + (long)n0 * 512 + (c - 10) * 256;  wstride = 512;  }

  for (int s = 0; s < 4; ++s) {
    int ks = s * 64;
#pragma unroll
    for (int j = 0; j < 8; ++j) {
      int f = tid + j * 256;
      int r = f >> 4, kk = (f & 15) * 4;
      const float* src;
      if (c < 2)       src = emb + (long)cap[r * TMAX_ + step] * E_ + c * 256 + ks + kk;
      else if (c < 10) src = ctx + (long)r * ENC_ + (c - 2) * 256 + ks + kk;
      else             src = h   + (long)r * H_   + (c - 10) * 256 + ks + kk;
      *(float4*)&As[r][kk] = *(const float4*)src;
    }
#pragma unroll
    for (int j = 0; j < 2; ++j) {
      int f = tid + j * 256;
      int r = f >> 4, kk = (f & 15) * 4;
      *(float4*)&Ws[r][kk] = *(const float4*)(Wbase + (long)r * wstride + ks + kk);
    }
    __syncthreads();
#pragma unroll 4
    for (int k4 = 0; k4 < 16; ++k4) {
      float4 a[4], w[4];
#pragma unroll
      for (int i = 0; i < 4; ++i) a[i] = *(const float4*)&As[mg + 32 * i][k4 * 4];
#pragma unroll
      for (int j = 0; j < 4; ++j) w[j] = *(const float4*)&Ws[ng + 8 * j][k4 * 4];
#pragma unroll
      for (int i = 0; i < 4; ++i)
#pragma unroll
        for (int j = 0; j < 4; ++j)
          acc[i][j] = fmaf(a[i].x, w[j].x,
                      fmaf(a[i].y, w[j].y,
                      fmaf(a[i].z, w[j].z,
                      fmaf(a[i].w, w[j].w, acc[i][j]))));
    }
    __syncthreads();
  }

  float* dst = part + (long)c * (128 * 1536);
#pragma unroll
  for (int i = 0; i < 4; ++i) {
    int m = mg + 32 * i;
#pragma unroll
    for (int j = 0; j < 4; ++j)
      dst[(long)m * 1536 + n0 + ng + 8 * j] = acc[i][j];
  }
}

// gate math summing the 12 partial slots + biases; writes h (f32) + h_bf.
__global__ __launch_bounds__(256) void k_gate2(const float* __restrict__ part,
                                               const float* __restrict__ b_ih,
                                               const float* __restrict__ b_hh,
                                               float* __restrict__ h,
                                               unsigned short* __restrict__ h_bf) {
  int idx = blockIdx.x * 256 + threadIdx.x;
  int b = idx >> 9, j = idx & 511;
  long o = (long)b * 1536 + j;
  const long PS = 128L * 1536;
  float gir = 0.f, giz = 0.f, gin = 0.f;
  float ghr = 0.f, ghz = 0.f, ghn = 0.f;
#pragma unroll
  for (int c = 0; c < 10; ++c) {
    gir += part[c * PS + o];
    giz += part[c * PS + o + 512];
    gin += part[c * PS + o + 1024];
  }
#pragma unroll
  for (int c = 10; c < 12; ++c) {
    ghr += part[c * PS + o];
    ghz += part[c * PS + o + 512];
    ghn += part[c * PS + o + 1024];
  }
  gir += b_ih[j];        ghr += b_hh[j];
  giz += b_ih[j + 512];  ghz += b_hh[j + 512];
  gin += b_ih[j + 1024]; ghn += b_hh[j + 1024];
  float r = 1.f / (1.f + __expf(-(gir + ghr)));
  float z = 1.f / (1.f + __expf(-(giz + ghz)));
  float nn = tanhf(gin + r * ghn);
  float hv = h[idx];
  float v = (1.f - z) * nn + z * hv;
  h[idx] = v;
  h_bf[idx] = f2b(v);
}

// ---------------------------------------------------------------------------
extern "C" void kernel_launch(void* const* d_in, const int* in_sizes, int n_in,
                              void* d_out, int out_size, void* d_ws, size_t ws_size,
                              hipStream_t stream) {
  const float* img    = (const float*)d_in[0];
  const int*   cap    = (const int*)d_in[1];
  const int*   caplen = (const int*)d_in[2];
  const float* emb    = (const float*)d_in[3];
  const float* We     = (const float*)d_in[4];
  const float* be     = (const float*)d_in[5];
  const float* Wd     = (const float*)d_in[6];
  const float* bd     = (const float*)d_in[7];
  const float* Wf     = (const float*)d_in[8];
  const float* bfp    = (const float*)d_in[9];
  const float* W_ih   = (const float*)d_in[10];
  const float* b_ih   = (const float*)d_in[11];
  const float* W_hh   = (const float*)d_in[12];
  const float* b_hh   = (const float*)d_in[13];
  const float* Wo     = (const float*)d_in[14];
  const float* bo     = (const float*)d_in[15];
  float* out = (float*)d_out;
  char*  W   = (char*)d_ws;

  unsigned short* att1_bf = (unsigned short*)(W + 0);
  unsigned short* WeT_bf  = (unsigned short*)(W + 25690112);
  unsigned short* WdT_bf  = (unsigned short*)(W + 27787264);
  unsigned short* Wo_bf   = (unsigned short*)(W + 28311552);
  float*          h       = (float*)(W + 48889856);
  unsigned short* h_bf    = (unsigned short*)(W + 49152000);
  float*          ctx     = (float*)(W + 49283072);
  float*          att2    = (float*)(W + 51904512);
  float*          alpha_w = (float*)(W + 52166656);
  unsigned short* img_bf  = (unsigned short*)(W + 52267008);
  float*          part    = (float*)(W + 155027456);   // 12*128*1536*4 = 9437184 B
  bool use_bfimg = ws_size >= 155027456ULL;
  bool use_part  = ws_size >= 164464640ULL;

  k_setup<<<10000, 256, 0, stream>>>(caplen, out, h, h_bf);
  k_cvt_t<<<dim3(64, 16), 256, 0, stream>>>(We, WeT_bf, ENC_, A_);
  k_cvt_t<<<dim3(16, 16), 256, 0, stream>>>(Wd, WdT_bf, H_, A_);
  k_cvt_wo<<<5024, 256, 0, stream>>>(Wo, Wo_bf);
  if (use_bfimg) {
    k_cvt_img<<<25088, 256, 0, stream>>>(img, img_bf);
    // att1 as pure bf16 NT GEMM with GLL16 staging (img_bf LLC-hot from cvt)
    k_gemm_nt<1><<<dim3(196, 4), 256, 0, stream>>>(img_bf, WeT_bf, be,
                                                   att1_bf, 512, 512, ENC_);
  } else {
    k_mfma_att1<<<dim3(196, 4), 256, 0, stream>>>(img, WeT_bf, be, att1_bf);
  }

  for (int i = 0; i < TMAX_ - 1; ++i) {
    int t = i + 1;
    k_gemm_nt<0><<<dim3(1, 4), 256, 0, stream>>>(h_bf, WdT_bf, bd,
                                                 att2, 512, 512, 512);
    k_attn_score<<<128, 256, 0, stream>>>(att1_bf, att2, Wf, bfp, alpha_w,
                                          out + ALPHA_OFF, ctx, t);
    if (use_bfimg)
      k_attn_ctx2<<<dim3(128, 7), 256, 0, stream>>>(img_bf, alpha_w, ctx);
    else
      k_attn_ctx<<<dim3(128, 4), 256, 0, stream>>>(img, alpha_w, ctx);
    if (use_part) {
      k_gru_part<<<dim3(48, 12), 256, 0, stream>>>(emb, cap, ctx, h, W_ih, W_hh,
                                                   part, i);
      k_gate2<<<256, 256, 0, stream>>>(part, b_ih, b_hh, h, h_bf);
    }
    k_gemm_nt<0><<<dim3(1, 157), 256, 0, stream>>>(h_bf, Wo_bf, bo,
                                                   out + (long)t * V_,
                                                   (long)TMAX_ * V_, V_, 512);
  }
}

// Round 5
// 2803.341 us; speedup vs baseline: 1.2882x; 1.2882x over previous
//
#include <hip/hip_runtime.h>
#include <hip/hip_bf16.h>

#define B_    128
#define P_    196
#define ENC_  2048
#define A_    512
#define E_    512
#define H_    512
#define V_    20000
#define TMAX_ 20

// ---- d_out layout (floats) ----
#define CAPLEN_OFF 51200000L
#define ALPHA_OFF  51200128L

typedef __attribute__((ext_vector_type(4))) float f32x4;
typedef __attribute__((ext_vector_type(8))) short bf16x8;

#define GLL16(gsrc, ldst) \
  __builtin_amdgcn_global_load_lds((__attribute__((address_space(1))) const void*)(gsrc), \
                                   (__attribute__((address_space(3))) void*)(ldst), 16, 0, 0)

__device__ __forceinline__ unsigned short f2b(float x) {
  union { float f; unsigned u; } v; v.f = x;
  unsigned r = v.u + 0x7FFF + ((v.u >> 16) & 1);
  return (unsigned short)(r >> 16);
}
__device__ __forceinline__ float b2f(unsigned short u) {
  union { unsigned u; float f; } v; v.u = ((unsigned)u) << 16; return v.f;
}

// ---------------------------------------------------------------------------
// Setup: predictions[:,0,:] one-hot, alphas[:,0,:]=0, caplen as float, h=0.
__global__ __launch_bounds__(256) void k_setup(const int* __restrict__ caplen,
                                               float* __restrict__ out,
                                               float* __restrict__ h,
                                               unsigned short* __restrict__ h_bf) {
  long idx = (long)blockIdx.x * 256 + threadIdx.x;
  if (idx < (long)B_ * V_) {
    long b = idx / V_, v = idx % V_;
    out[b * (long)TMAX_ * V_ + v] = (v == 1) ? 1.0f : 0.0f;
  }
  if (idx < B_) out[CAPLEN_OFF + idx] = (float)caplen[idx];
  if (idx < (long)B_ * P_) {
    long b = idx / P_, p = idx % P_;
    out[ALPHA_OFF + b * (long)(TMAX_ * P_) + p] = 0.0f;
  }
  if (idx < B_ * H_) { h[idx] = 0.0f; h_bf[idx] = 0; }
}

// ---------------------------------------------------------------------------
// Transpose + convert: src [R,C] f32 -> dst [C,R] bf16.  grid (R/32, C/32).
__global__ __launch_bounds__(256) void k_cvt_t(const float* __restrict__ src,
                                               unsigned short* __restrict__ dst,
                                               int R, int C) {
  __shared__ float tile[32][33];
  int lx = threadIdx.x & 31, ly = threadIdx.x >> 5;
  int r0 = blockIdx.x * 32, c0 = blockIdx.y * 32;
#pragma unroll
  for (int j = 0; j < 32; j += 8)
    tile[ly + j][lx] = src[(long)(r0 + ly + j) * C + c0 + lx];
  __syncthreads();
#pragma unroll
  for (int j = 0; j < 32; j += 8)
    dst[(long)(c0 + ly + j) * R + r0 + lx] = f2b(tile[lx][ly + j]);
}

// Wo [20000,512] f32 -> Wo_bf [20096,512] bf16 (pad rows zero). grid 5024.
__global__ __launch_bounds__(256) void k_cvt_wo(const float* __restrict__ Wo,
                                                unsigned short* __restrict__ Wo_bf) {
  long gid = (long)blockIdx.x * 256 + threadIdx.x;
  long base = gid * 8;
  if (base >= (long)20096 * 512) return;
  long row = base >> 9;
  bf16x8 u;
  if (row < V_) {
    float4 f0 = *(const float4*)(Wo + base);
    float4 f1 = *(const float4*)(Wo + base + 4);
    u[0] = (short)f2b(f0.x); u[1] = (short)f2b(f0.y);
    u[2] = (short)f2b(f0.z); u[3] = (short)f2b(f0.w);
    u[4] = (short)f2b(f1.x); u[5] = (short)f2b(f1.y);
    u[6] = (short)f2b(f1.z); u[7] = (short)f2b(f1.w);
  } else {
    for (int j = 0; j < 8; ++j) u[j] = 0;
  }
  *(bf16x8*)(Wo_bf + base) = u;
}

// img f32 -> img_bf bf16, 8 elems/thread.  grid 25088.
__global__ __launch_bounds__(256) void k_cvt_img(const float* __restrict__ img,
                                                 unsigned short* __restrict__ img_bf) {
  long base = ((long)blockIdx.x * 256 + threadIdx.x) * 8;
  float4 f0 = *(const float4*)(img + base);
  float4 f1 = *(const float4*)(img + base + 4);
  bf16x8 u;
  u[0] = (short)f2b(f0.x); u[1] = (short)f2b(f0.y);
  u[2] = (short)f2b(f0.z); u[3] = (short)f2b(f0.w);
  u[4] = (short)f2b(f1.x); u[5] = (short)f2b(f1.y);
  u[6] = (short)f2b(f1.z); u[7] = (short)f2b(f1.w);
  *(bf16x8*)(img_bf + base) = u;
}

// ---------------------------------------------------------------------------
// MFMA NT GEMM: C[M,N] = A_bf[M,K] @ B_bf[N,K]^T + bias.
// Tile 128x128, BK=32, 4 waves (2x2 of 64x64), 16x16x32 bf16 MFMA.
// LDS chunk-swizzled (G21: linear GLL16 dest + pre-swizzled global source +
// matching swizzled ds_read) -> conflict-free ds_read_b128 (was 8-way).
// OBF=1 -> bf16 output, OBF=0 -> f32 output.  bias may be null.
template <int OBF>
__global__ __launch_bounds__(256) void k_gemm_nt(const unsigned short* __restrict__ Abf,
                                                 const unsigned short* __restrict__ Bbf,
                                                 const float* __restrict__ bias,
                                                 void* __restrict__ Cv, long ldc,
                                                 int N, int K) {
  __shared__ unsigned short As[4096];
  __shared__ unsigned short Bs[4096];
  int tid = threadIdx.x, wave = tid >> 6, lane = tid & 63;
  int m0 = blockIdx.x * 128, n0 = blockIdx.y * 128;
  int wm = (wave & 1) * 64, wn = (wave >> 1) * 64;
  int rowL = tid >> 2;
  // source chunk swizzle: lane (tid&3) loads chunk (tid&3)^((tid>>3)&3)
  int chkL = (((tid & 3) ^ ((tid >> 3) & 3))) * 8;
  const unsigned short* gA0 = Abf + (long)(m0 + rowL) * K + chkL;
  const unsigned short* gA1 = gA0 + (long)64 * K;
  const unsigned short* gB0 = Bbf + (long)(n0 + rowL) * K + chkL;
  const unsigned short* gB1 = gB0 + (long)64 * K;
  unsigned short* ldsA = As + wave * 512;
  unsigned short* ldsB = Bs + wave * 512;

  f32x4 acc[4][4];
#pragma unroll
  for (int i = 0; i < 4; ++i)
#pragma unroll
    for (int j = 0; j < 4; ++j) acc[i][j] = (f32x4){0.f, 0.f, 0.f, 0.f};

  int fm = lane & 15, q = lane >> 4;
  // read-side swizzled chunk (row bits 1,2 come from fm for all tiles)
  int qs = (q ^ ((fm >> 1) & 3)) * 8;
  for (int kc = 0; kc < K; kc += 32) {
    GLL16(gA0 + kc, ldsA);
    GLL16(gA1 + kc, ldsA + 2048);
    GLL16(gB0 + kc, ldsB);
    GLL16(gB1 + kc, ldsB + 2048);
    __syncthreads();
    bf16x8 af[4], bfr[4];
#pragma unroll
    for (int i = 0; i < 4; ++i)
      af[i] = *(const bf16x8*)&As[(wm + i * 16 + fm) * 32 + qs];
#pragma unroll
    for (int j = 0; j < 4; ++j)
      bfr[j] = *(const bf16x8*)&Bs[(wn + j * 16 + fm) * 32 + qs];
#pragma unroll
    for (int i = 0; i < 4; ++i)
#pragma unroll
      for (int j = 0; j < 4; ++j)
        acc[i][j] = __builtin_amdgcn_mfma_f32_16x16x32_bf16(af[i], bfr[j], acc[i][j], 0, 0, 0);
    __syncthreads();
  }
  int q4 = (lane >> 4) * 4;
#pragma unroll
  for (int i = 0; i < 4; ++i)
#pragma unroll
    for (int j = 0; j < 4; ++j) {
      int n = n0 + wn + j * 16 + fm;
      if (n < N) {
        float bv = bias ? bias[n] : 0.f;
#pragma unroll
        for (int r = 0; r < 4; ++r) {
          long m = m0 + wm + i * 16 + q4 + r;
          if (OBF) ((unsigned short*)Cv)[m * ldc + n] = f2b(acc[i][j][r] + bv);
          else     ((float*)Cv)[m * ldc + n] = acc[i][j][r] + bv;
        }
      }
    }
}

// ---------------------------------------------------------------------------
// Fallback att1 MFMA (f32 A with fused convert) — only used if img_bf absent.
__global__ __launch_bounds__(256) void k_mfma_att1(const float* __restrict__ Aimg,
                                                   const unsigned short* __restrict__ Bbf,
                                                   const float* __restrict__ bias,
                                                   unsigned short* __restrict__ C) {
  __shared__ unsigned short As[4096];
  __shared__ unsigned short Bs[4096];
  int tid = threadIdx.x, wave = tid >> 6, lane = tid & 63;
  int m0 = blockIdx.x * 128, n0 = blockIdx.y * 128;
  int wm = (wave & 1) * 64, wn = (wave >> 1) * 64;
  int rowA = tid >> 1, segA = (tid & 1) * 16;
  const float* gA = Aimg + (long)(m0 + rowA) * ENC_ + segA;
  int rowL = tid >> 2, chkL = (tid & 3) * 8;
  const unsigned short* gB0 = Bbf + (long)(n0 + rowL) * ENC_ + chkL;
  const unsigned short* gB1 = gB0 + (long)64 * ENC_;
  unsigned short* ldsB = Bs + wave * 512;

  f32x4 acc[4][4];
#pragma unroll
  for (int i = 0; i < 4; ++i)
#pragma unroll
    for (int j = 0; j < 4; ++j) acc[i][j] = (f32x4){0.f, 0.f, 0.f, 0.f};

  int fm = lane & 15, q8 = (lane >> 4) * 8;
  for (int kc = 0; kc < ENC_; kc += 32) {
    GLL16(gB0 + kc, ldsB);
    GLL16(gB1 + kc, ldsB + 2048);
    float4 f0 = *(const float4*)(gA + kc);
    float4 f1 = *(const float4*)(gA + kc + 4);
    float4 f2 = *(const float4*)(gA + kc + 8);
    float4 f3 = *(const float4*)(gA + kc + 12);
    bf16x8 u0, u1;
    u0[0] = (short)f2b(f0.x); u0[1] = (short)f2b(f0.y);
    u0[2] = (short)f2b(f0.z); u0[3] = (short)f2b(f0.w);
    u0[4] = (short)f2b(f1.x); u0[5] = (short)f2b(f1.y);
    u0[6] = (short)f2b(f1.z); u0[7] = (short)f2b(f1.w);
    u1[0] = (short)f2b(f2.x); u1[1] = (short)f2b(f2.y);
    u1[2] = (short)f2b(f2.z); u1[3] = (short)f2b(f2.w);
    u1[4] = (short)f2b(f3.x); u1[5] = (short)f2b(f3.y);
    u1[6] = (short)f2b(f3.z); u1[7] = (short)f2b(f3.w);
    *(bf16x8*)&As[rowA * 32 + segA] = u0;
    *(bf16x8*)&As[rowA * 32 + segA + 8] = u1;
    __syncthreads();
    bf16x8 af[4], bfr[4];
#pragma unroll
    for (int i = 0; i < 4; ++i)
      af[i] = *(const bf16x8*)&As[(wm + i * 16 + fm) * 32 + q8];
#pragma unroll
    for (int j = 0; j < 4; ++j)
      bfr[j] = *(const bf16x8*)&Bs[(wn + j * 16 + fm) * 32 + q8];
#pragma unroll
    for (int i = 0; i < 4; ++i)
#pragma unroll
      for (int j = 0; j < 4; ++j)
        acc[i][j] = __builtin_amdgcn_mfma_f32_16x16x32_bf16(af[i], bfr[j], acc[i][j], 0, 0, 0);
    __syncthreads();
  }
  int q4 = (lane >> 4) * 4;
#pragma unroll
  for (int i = 0; i < 4; ++i)
#pragma unroll
    for (int j = 0; j < 4; ++j) {
      int n = n0 + wn + j * 16 + fm;
      float bv = bias[n];
#pragma unroll
      for (int r = 0; r < 4; ++r) {
        long m = m0 + wm + i * 16 + q4 + r;
        C[m * 512 + n] = f2b(acc[i][j][r] + bv);
      }
    }
}

// ---------------------------------------------------------------------------
// scores + softmax + alpha.  One block per b.
__global__ __launch_bounds__(256) void k_attn_score(const unsigned short* __restrict__ att1_bf,
                                                    const float* __restrict__ att2,
                                                    const float* __restrict__ Wf,
                                                    const float* __restrict__ bfp,
                                                    float* __restrict__ alpha_ws,
                                                    float* __restrict__ out_alpha,
                                                    int t) {
  int b = blockIdx.x, tid = threadIdx.x;
  int wave = tid >> 6, lane = tid & 63;
  __shared__ float sc[P_ + 4];
  __shared__ float red[8];

  float a2[8], w8[8];
  {
    const float* ap = att2 + (long)b * 512 + lane * 8;
    float4 x0 = *(const float4*)ap, x1 = *(const float4*)(ap + 4);
    a2[0] = x0.x; a2[1] = x0.y; a2[2] = x0.z; a2[3] = x0.w;
    a2[4] = x1.x; a2[5] = x1.y; a2[6] = x1.z; a2[7] = x1.w;
    const float* wp = Wf + lane * 8;
    float4 y0 = *(const float4*)wp, y1 = *(const float4*)(wp + 4);
    w8[0] = y0.x; w8[1] = y0.y; w8[2] = y0.z; w8[3] = y0.w;
    w8[4] = y1.x; w8[5] = y1.y; w8[6] = y1.z; w8[7] = y1.w;
  }
  float bias0 = bfp[0];

  for (int p = wave; p < P_; p += 4) {
    bf16x8 v = *(const bf16x8*)(att1_bf + ((long)(b * P_ + p)) * 512 + lane * 8);
    float part = 0.f;
#pragma unroll
    for (int j = 0; j < 8; ++j) {
      float x = b2f((unsigned short)v[j]) + a2[j];
      part = fmaf(fmaxf(x, 0.f), w8[j], part);
    }
#pragma unroll
    for (int off = 32; off > 0; off >>= 1) part += __shfl_down(part, off);
    if (lane == 0) sc[p] = part + bias0;
  }
  __syncthreads();

  float mv = (tid < P_) ? sc[tid] : -1e30f;
#pragma unroll
  for (int off = 32; off > 0; off >>= 1) mv = fmaxf(mv, __shfl_down(mv, off));
  if (lane == 0) red[wave] = mv;
  __syncthreads();
  if (tid == 0) red[4] = fmaxf(fmaxf(red[0], red[1]), fmaxf(red[2], red[3]));
  __syncthreads();
  float mx = red[4];
  float e = (tid < P_) ? __expf(sc[tid] - mx) : 0.f;
  float sm = e;
#pragma unroll
  for (int off = 32; off > 0; off >>= 1) sm += __shfl_down(sm, off);
  if (lane == 0) red[wave] = sm;
  __syncthreads();
  if (tid == 0) red[5] = red[0] + red[1] + red[2] + red[3];
  __syncthreads();
  float inv = 1.f / red[5];
  if (tid < P_) {
    float al = e * inv;
    alpha_ws[b * P_ + tid] = al;
    out_alpha[((long)b * TMAX_ + t) * P_ + tid] = al;
  }
}

// ---------------------------------------------------------------------------
// ctx partials, p-split: grid (128, 7).  Block (b, pc): 28 full-ENC rows,
// coalesced 4KB row loads, partial sum -> pctx[pc][b][:] (no atomics).
__global__ __launch_bounds__(256) void k_ctx_part(const unsigned short* __restrict__ img_bf,
                                                  const float* __restrict__ alpha_ws,
                                                  float* __restrict__ pctx) {
  int b = blockIdx.x, pc = blockIdx.y;
  int tid = threadIdx.x;
  __shared__ float als[28];
  if (tid < 28) als[tid] = alpha_ws[b * P_ + pc * 28 + tid];
  __syncthreads();
  float acc[8];
#pragma unroll
  for (int j = 0; j < 8; ++j) acc[j] = 0.f;
  const unsigned short* base = img_bf + ((long)b * P_ + pc * 28) * ENC_ + tid * 8;
#pragma unroll 4
  for (int p = 0; p < 28; ++p) {
    bf16x8 v = *(const bf16x8*)(base + (long)p * ENC_);
    float al = als[p];
#pragma unroll
    for (int j = 0; j < 8; ++j) acc[j] = fmaf(al, b2f((unsigned short)v[j]), acc[j]);
  }
  float* dst = pctx + ((long)pc * B_ + b) * ENC_ + tid * 8;
  *(float4*)dst = (float4){acc[0], acc[1], acc[2], acc[3]};
  *(float4*)(dst + 4) = (float4){acc[4], acc[5], acc[6], acc[7]};
}

// sum the 7 p-partials -> ctx.  grid 256 (256*256*4 = 128*2048 floats).
__global__ __launch_bounds__(256) void k_ctx_reduce(const float* __restrict__ pctx,
                                                    float* __restrict__ ctx) {
  long idx = ((long)blockIdx.x * 256 + threadIdx.x) * 4;
  const long PS = (long)B_ * ENC_;
  float4 s = *(const float4*)(pctx + idx);
#pragma unroll
  for (int pc = 1; pc < 7; ++pc) {
    float4 v = *(const float4*)(pctx + pc * PS + idx);
    s.x += v.x; s.y += v.y; s.z += v.z; s.w += v.w;
  }
  *(float4*)(ctx + idx) = s;
}

// Fallback ctx (f32 img, no img_bf).  grid (128, 4).
__global__ __launch_bounds__(256) void k_attn_ctx(const float* __restrict__ img,
                                                  const float* __restrict__ alpha_ws,
                                                  float* __restrict__ ctx) {
  int b = blockIdx.x, ec = blockIdx.y;
  int tid = threadIdx.x, wave = tid >> 6, lane = tid & 63;
  __shared__ float als[P_];
  __shared__ float part[4][512];
  if (tid < P_) als[tid] = alpha_ws[b * P_ + tid];
  __syncthreads();
  float acc[8];
#pragma unroll
  for (int j = 0; j < 8; ++j) acc[j] = 0.f;
  long base = (long)b * P_ * ENC_ + ec * 512 + lane * 8;
  for (int p = wave; p < P_; p += 4) {
    float al = als[p];
    const float* r = img + base + (long)p * ENC_;
    float4 v0 = *(const float4*)r, v1 = *(const float4*)(r + 4);
    acc[0] = fmaf(al, v0.x, acc[0]); acc[1] = fmaf(al, v0.y, acc[1]);
    acc[2] = fmaf(al, v0.z, acc[2]); acc[3] = fmaf(al, v0.w, acc[3]);
    acc[4] = fmaf(al, v1.x, acc[4]); acc[5] = fmaf(al, v1.y, acc[5]);
    acc[6] = fmaf(al, v1.z, acc[6]); acc[7] = fmaf(al, v1.w, acc[7]);
  }
#pragma unroll
  for (int j = 0; j < 8; ++j) part[wave][lane * 8 + j] = acc[j];
  __syncthreads();
  for (int e = tid; e < 512; e += 256) {
    float s = part[0][e] + part[1][e] + part[2][e] + part[3][e];
    ctx[(long)b * ENC_ + ec * 512 + e] = s;
  }
}

// ---------------------------------------------------------------------------
// split-K GRU gate GEMM partials, f32.  grid (48, 12).
__global__ __launch_bounds__(256) void k_gru_part(const float* __restrict__ emb,
                                                  const int* __restrict__ cap,
                                                  const float* __restrict__ ctx,
                                                  const float* __restrict__ h,
                                                  const float* __restrict__ W_ih,
                                                  const float* __restrict__ W_hh,
                                                  float* __restrict__ part,
                                                  int step) {
  __shared__ float As[128][68];
  __shared__ float Ws[32][68];
  int n0 = blockIdx.x * 32;
  int c  = blockIdx.y;
  int tid = threadIdx.x;
  int ng = tid & 7, mg = tid >> 3;

  float acc[4][4];
#pragma unroll
  for (int i = 0; i < 4; ++i)
#pragma unroll
    for (int j = 0; j < 4; ++j) acc[i][j] = 0.f;

  const float* Wbase;
  long wstride;
  if (c < 10) { Wbase = W_ih + (long)n0 * 2560 + c * 256;        wstride = 2560; }
  else        { Wbase = W_hh + (long)n0 * 512 + (c - 10) * 256;  wstride = 512;  }

  for (int s = 0; s < 4; ++s) {
    int ks = s * 64;
#pragma unroll
    for (int j = 0; j < 8; ++j) {
      int f = tid + j * 256;
      int r = f >> 4, kk = (f & 15) * 4;
      const float* src;
      if (c < 2)       src = emb + (long)cap[r * TMAX_ + step] * E_ + c * 256 + ks + kk;
      else if (c < 10) src = ctx + (long)r * ENC_ + (c - 2) * 256 + ks + kk;
      else             src = h   + (long)r * H_   + (c - 10) * 256 + ks + kk;
      *(float4*)&As[r][kk] = *(const float4*)src;
    }
#pragma unroll
    for (int j = 0; j < 2; ++j) {
      int f = tid + j * 256;
      int r = f >> 4, kk = (f & 15) * 4;
      *(float4*)&Ws[r][kk] = *(const float4*)(Wbase + (long)r * wstride + ks + kk);
    }
    __syncthreads();
#pragma unroll 4
    for (int k4 = 0; k4 < 16; ++k4) {
      float4 a[4], w[4];
#pragma unroll
      for (int i = 0; i < 4; ++i) a[i] = *(const float4*)&As[mg + 32 * i][k4 * 4];
#pragma unroll
      for (int j = 0; j < 4; ++j) w[j] = *(const float4*)&Ws[ng + 8 * j][k4 * 4];
#pragma unroll
      for (int i = 0; i < 4; ++i)
#pragma unroll
        for (int j = 0; j < 4; ++j)
          acc[i][j] = fmaf(a[i].x, w[j].x,
                      fmaf(a[i].y, w[j].y,
                      fmaf(a[i].z, w[j].z,
                      fmaf(a[i].w, w[j].w, acc[i][j]))));
    }
    __syncthreads();
  }

  float* dst = part + (long)c * (128 * 1536);
#pragma unroll
  for (int i = 0; i < 4; ++i) {
    int m = mg + 32 * i;
#pragma unroll
    for (int j = 0; j < 4; ++j)
      dst[(long)m * 1536 + n0 + ng + 8 * j] = acc[i][j];
  }
}

// gate math summing the 12 partial slots + biases; writes h (f32) + h_bf.
__global__ __launch_bounds__(256) void k_gate2(const float* __restrict__ part,
                                               const float* __restrict__ b_ih,
                                               const float* __restrict__ b_hh,
                                               float* __restrict__ h,
                                               unsigned short* __restrict__ h_bf) {
  int idx = blockIdx.x * 256 + threadIdx.x;
  int b = idx >> 9, j = idx & 511;
  long o = (long)b * 1536 + j;
  const long PS = 128L * 1536;
  float gir = 0.f, giz = 0.f, gin = 0.f;
  float ghr = 0.f, ghz = 0.f, ghn = 0.f;
#pragma unroll
  for (int c = 0; c < 10; ++c) {
    gir += part[c * PS + o];
    giz += part[c * PS + o + 512];
    gin += part[c * PS + o + 1024];
  }
#pragma unroll
  for (int c = 10; c < 12; ++c) {
    ghr += part[c * PS + o];
    ghz += part[c * PS + o + 512];
    ghn += part[c * PS + o + 1024];
  }
  gir += b_ih[j];        ghr += b_hh[j];
  giz += b_ih[j + 512];  ghz += b_hh[j + 512];
  gin += b_ih[j + 1024]; ghn += b_hh[j + 1024];
  float r = 1.f / (1.f + __expf(-(gir + ghr)));
  float z = 1.f / (1.f + __expf(-(giz + ghz)));
  float nn = tanhf(gin + r * ghn);
  float hv = h[idx];
  float v = (1.f - z) * nn + z * hv;
  h[idx] = v;
  h_bf[idx] = f2b(v);
}

// ---------------------------------------------------------------------------
extern "C" void kernel_launch(void* const* d_in, const int* in_sizes, int n_in,
                              void* d_out, int out_size, void* d_ws, size_t ws_size,
                              hipStream_t stream) {
  const float* img    = (const float*)d_in[0];
  const int*   cap    = (const int*)d_in[1];
  const int*   caplen = (const int*)d_in[2];
  const float* emb    = (const float*)d_in[3];
  const float* We     = (const float*)d_in[4];
  const float* be     = (const float*)d_in[5];
  const float* Wd     = (const float*)d_in[6];
  const float* bd     = (const float*)d_in[7];
  const float* Wf     = (const float*)d_in[8];
  const float* bfp    = (const float*)d_in[9];
  const float* W_ih   = (const float*)d_in[10];
  const float* b_ih   = (const float*)d_in[11];
  const float* W_hh   = (const float*)d_in[12];
  const float* b_hh   = (const float*)d_in[13];
  const float* Wo     = (const float*)d_in[14];
  const float* bo     = (const float*)d_in[15];
  float* out = (float*)d_out;
  char*  W   = (char*)d_ws;

  unsigned short* att1_bf = (unsigned short*)(W + 0);
  unsigned short* WeT_bf  = (unsigned short*)(W + 25690112);
  unsigned short* WdT_bf  = (unsigned short*)(W + 27787264);
  unsigned short* Wo_bf   = (unsigned short*)(W + 28311552);
  float*          h       = (float*)(W + 48889856);
  unsigned short* h_bf    = (unsigned short*)(W + 49152000);
  float*          ctx     = (float*)(W + 49283072);
  float*          att2    = (float*)(W + 51904512);
  float*          alpha_w = (float*)(W + 52166656);
  unsigned short* img_bf  = (unsigned short*)(W + 52267008);
  float*          part    = (float*)(W + 155027456);   // 12*128*1536*4 = 9437184 B
  // pctx (7*128*2048*4 = 7340032 B) REUSES part: ctx partials are fully
  // consumed by k_ctx_reduce before k_gru_part overwrites part (stream order).
  float*          pctx    = part;
  bool use_bfimg = ws_size >= 155027456ULL;
  bool use_part  = ws_size >= 164464640ULL;

  k_setup<<<10000, 256, 0, stream>>>(caplen, out, h, h_bf);
  k_cvt_t<<<dim3(64, 16), 256, 0, stream>>>(We, WeT_bf, ENC_, A_);
  k_cvt_t<<<dim3(16, 16), 256, 0, stream>>>(Wd, WdT_bf, H_, A_);
  k_cvt_wo<<<5024, 256, 0, stream>>>(Wo, Wo_bf);
  if (use_bfimg) {
    k_cvt_img<<<25088, 256, 0, stream>>>(img, img_bf);
    k_gemm_nt<1><<<dim3(196, 4), 256, 0, stream>>>(img_bf, WeT_bf, be,
                                                   att1_bf, 512, 512, ENC_);
  } else {
    k_mfma_att1<<<dim3(196, 4), 256, 0, stream>>>(img, WeT_bf, be, att1_bf);
  }

  for (int i = 0; i < TMAX_ - 1; ++i) {
    int t = i + 1;
    k_gemm_nt<0><<<dim3(1, 4), 256, 0, stream>>>(h_bf, WdT_bf, bd,
                                                 att2, 512, 512, 512);
    k_attn_score<<<128, 256, 0, stream>>>(att1_bf, att2, Wf, bfp, alpha_w,
                                          out + ALPHA_OFF, t);
    if (use_bfimg && use_part) {
      k_ctx_part<<<dim3(128, 7), 256, 0, stream>>>(img_bf, alpha_w, pctx);
      k_ctx_reduce<<<256, 256, 0, stream>>>(pctx, ctx);
    } else {
      k_attn_ctx<<<dim3(128, 4), 256, 0, stream>>>(img, alpha_w, ctx);
    }
    if (use_part) {
      k_gru_part<<<dim3(48, 12), 256, 0, stream>>>(emb, cap, ctx, h, W_ih, W_hh,
                                                   part, i);
      k_gate2<<<256, 256, 0, stream>>>(part, b_ih, b_hh, h, h_bf);
    }
    k_gemm_nt<0><<<dim3(1, 157), 256, 0, stream>>>(h_bf, Wo_bf, bo,
                                                   out + (long)t * V_,
                                                   (long)TMAX_ * V_, V_, 512);
  }
}